// Round 7
// baseline (338.245 us; speedup 1.0000x reference)
//
#include <hip/hip_runtime.h>
#include <math.h>

#define N_NODES 100000
#define N_FEAT  256
#define K_SEL   50000
#define N_EDGES 3200000
#define NBUCKET 65536
#define NCHUNK  256                         /* NBUCKET / 256 bins per chunk */

#define GATHER_BLOCKS (K_SEL / 4)           /* 4 rows (64 lanes ea) per 256-thr block */
#define EDGE_BLOCKS   (N_EDGES / (4 * 256)) /* 4 edges per thread */

typedef float __attribute__((ext_vector_type(4))) floatx4;
typedef int   __attribute__((ext_vector_type(4))) intx4;

// ---- key encodings -------------------------------------------------------
// ascending uint64 key == descending z, so stable-ascending == top_k order
__device__ __forceinline__ unsigned long long descKey(double z) {
    unsigned long long u = (unsigned long long)__double_as_longlong(z);
    unsigned long long a = (u >> 63) ? ~u : (u | 0x8000000000000000ULL);
    return ~a;
}

// exact inverse of descKey (bit-exact roundtrip, finite values)
__device__ __forceinline__ double invKey(unsigned long long k) {
    unsigned long long a = ~k;
    unsigned long long u = (a >> 63) ? (a & 0x7FFFFFFFFFFFFFFFULL) : ~a;
    return __longlong_as_double((long long)u);
}

__device__ __forceinline__ unsigned int bucketOfFloat(float zf) {
    unsigned int u = __float_as_uint(zf);
    unsigned int a = (u >> 31) ? ~u : (u | 0x80000000u);
    return (~a) >> 16;
}

// ---- kernels -------------------------------------------------------------
// init: FIRST dispatch in the chain, as in R0/R1 (307-320us totals).
// Zero hist + scan counter; block 0 computes ||w|| in fp64.  R3-R6 replaced
// this with hipMemsetAsync and totals jumped +29us with score inflating
// 59->84us at idle counters — leading-kernel-vs-memset is the only code
// delta correlated with that jump (absorbs the harness poison-fill drain).
__global__ void init_kernel(const float* __restrict__ w, double* __restrict__ norm,
                            int* __restrict__ hist, int* __restrict__ counter) {
    __shared__ double sd[256];
    int t = blockIdx.x * blockDim.x + threadIdx.x;
    hist[t] = 0;
    if (t == 0) counter[0] = 0;
    if (blockIdx.x == 0) {
        int tt = threadIdx.x;
        double v = (double)w[tt];
        sd[tt] = v * v;
        __syncthreads();
        for (int off = 128; off > 0; off >>= 1) {
            if (tt < off) sd[tt] += sd[tt + off];
            __syncthreads();
        }
        if (tt == 0) norm[0] = sqrt(sd[0]);
    }
}

// score: R1 form. One wave per row: x-read is one fully-coalesced 1KB load
// instruction (64 lanes x 16B contiguous). fp64 accumulate; ranking is
// monotone in the raw dot -> no norm, no tanh here.
__global__ void score_kernel(const float* __restrict__ x, const float* __restrict__ w,
                             unsigned long long* __restrict__ key64,
                             int* __restrict__ hist) {
    int row  = (int)((blockIdx.x * blockDim.x + threadIdx.x) >> 6);
    int lane = threadIdx.x & 63;
    if (row >= N_NODES) return;
    const float4 xv = ((const float4*)(x + (size_t)row * N_FEAT))[lane];
    const float4 wv = ((const float4*)w)[lane];
    double acc = (double)xv.x * (double)wv.x + (double)xv.y * (double)wv.y +
                 (double)xv.z * (double)wv.z + (double)xv.w * (double)wv.w;
    for (int m = 32; m >= 1; m >>= 1) acc += __shfl_xor(acc, m, 64);
    if (lane == 0) {
        key64[row] = descKey(acc);
        atomicAdd(&hist[bucketOfFloat((float)acc)], 1);
    }
}

// chunked scan: block c scans its 256 bins into chunk-LOCAL exclusive
// prefixes (-> start[]); last-arriving block scans the 256 chunk totals into
// chunkOff[].  Consumers add chunkOff[b>>8] on the fly.
__global__ void __launch_bounds__(256) scan_kernel(const int* __restrict__ hist,
                                                   int* __restrict__ start,
                                                   int* __restrict__ chunkSums,
                                                   int* __restrict__ chunkOff,
                                                   int* __restrict__ counter) {
    __shared__ int s[256];
    __shared__ int lastFlag;
    int c = blockIdx.x, t = threadIdx.x;
    int v = hist[c * 256 + t];
    s[t] = v;
    __syncthreads();
    for (int off = 1; off < 256; off <<= 1) {
        int add = (t >= off) ? s[t - off] : 0;
        __syncthreads();
        s[t] += add;
        __syncthreads();
    }
    start[c * 256 + t] = s[t] - v; /* chunk-local exclusive prefix */
    if (t == 0) {
        atomicExch(&chunkSums[c], s[255]);   /* device-scope publish */
        __threadfence();
        int old = atomicAdd(counter, 1);
        lastFlag = (old == NCHUNK - 1);
    }
    __syncthreads();
    if (!lastFlag) return;
    int wsum = atomicAdd(&chunkSums[t], 0);  /* device-coherent read */
    __syncthreads();
    s[t] = wsum;
    __syncthreads();
    for (int off = 1; off < 256; off <<= 1) {
        int add = (t >= off) ? s[t - off] : 0;
        __syncthreads();
        s[t] += add;
        __syncthreads();
    }
    chunkOff[t] = s[t] - wsum; /* global exclusive offset of chunk t */
}

// scatter nodes to their bucket's slot range; consumes start[] via atomicAdd
__global__ void scatter_kernel(const unsigned long long* __restrict__ key64,
                               int* __restrict__ start,
                               const int* __restrict__ chunkOff,
                               unsigned long long* __restrict__ slotKey,
                               int* __restrict__ slotIdx) {
    int i = blockIdx.x * blockDim.x + threadIdx.x;
    if (i >= N_NODES) return;
    unsigned long long k = key64[i];
    int b = (int)bucketOfFloat((float)invKey(k));
    int pos = atomicAdd(&start[b], 1) + chunkOff[b >> 8];
    slotKey[pos] = k;
    slotIdx[pos] = i;
}

// exact rank within bucket via fp64 key + index tie-break.
// post-scatter start[b]+chunkOff == bucket end; begin = end - hist[b].
// buckets entirely below the cutoff (st >= K) short-circuit to mapping=-1.
__global__ void rank_kernel(const unsigned long long* __restrict__ slotKey,
                            const int* __restrict__ slotIdx,
                            const int* __restrict__ start, const int* __restrict__ hist,
                            const int* __restrict__ chunkOff,
                            float* __restrict__ mappingF, int* __restrict__ perm,
                            float* __restrict__ selDot) {
    int s = blockIdx.x * blockDim.x + threadIdx.x;
    if (s >= N_NODES) return;
    unsigned long long myKey = slotKey[s];
    int i = slotIdx[s];
    float df = (float)invKey(myKey);
    int b = (int)bucketOfFloat(df);
    int end = start[b] + chunkOff[b >> 8];
    int cnt = hist[b];
    int st = end - cnt;
    if (st >= K_SEL) {                        /* whole bucket below cutoff */
        mappingF[i] = -1.0f;
        return;
    }
    int rank = 0;
    if (cnt > 1) {
        for (int q = st; q < end; ++q) {
            unsigned long long k = slotKey[q];
            if (k < myKey || (k == myKey && slotIdx[q] < i)) ++rank;
        }
    }
    int p = st + rank;
    if (p < K_SEL) {
        mappingF[i] = (float)p;
        perm[p] = i;
        selDot[p] = df;
    } else {
        mappingF[i] = -1.0f;
    }
}

// fused output: blocks [0,GATHER_BLOCKS) gather+gate x rows (tanh here, fp32,
// selected rows only); blocks [GATHER_BLOCKS,...) remap edges, 4/thread int4
__global__ void out_kernel(const float* __restrict__ x, const int* __restrict__ perm,
                           const float* __restrict__ selDot,
                           const double* __restrict__ normp,
                           const int* __restrict__ ei,
                           const float* __restrict__ mappingF,
                           float* __restrict__ out) {
    if (blockIdx.x < GATHER_BLOCKS) {
        int tid = blockIdx.x * 256 + threadIdx.x;
        int r = tid >> 6;
        int c = (tid & 63) << 2;
        int src = perm[r];
        float sc = tanhf(selDot[r] / (float)normp[0]);
        float4 v = *(const float4*)(x + (size_t)src * N_FEAT + c);
        floatx4 o;
        o.x = v.x * sc; o.y = v.y * sc; o.z = v.z * sc; o.w = v.w * sc;
        __builtin_nontemporal_store(o, (floatx4*)(out + (size_t)r * N_FEAT + c));
    } else {
        int tid = (blockIdx.x - GATHER_BLOCKS) * 256 + threadIdx.x;
        int e = tid << 2;
        intx4 a = __builtin_nontemporal_load((const intx4*)(ei + e));
        intx4 b = __builtin_nontemporal_load((const intx4*)(ei + N_EDGES + e));
        float* oeu = out + (size_t)K_SEL * N_FEAT;
        float* oev = oeu + N_EDGES;
        float m0 = mappingF[a.x], m1 = mappingF[a.y];
        float m2 = mappingF[a.z], m3 = mappingF[a.w];
        float n0 = mappingF[b.x], n1 = mappingF[b.y];
        float n2 = mappingF[b.z], n3 = mappingF[b.w];
        floatx4 ou, ov;
        bool v0 = (m0 >= 0.0f) && (n0 >= 0.0f);
        bool v1 = (m1 >= 0.0f) && (n1 >= 0.0f);
        bool v2 = (m2 >= 0.0f) && (n2 >= 0.0f);
        bool v3 = (m3 >= 0.0f) && (n3 >= 0.0f);
        ou.x = v0 ? m0 : -1.0f; ov.x = v0 ? n0 : -1.0f;
        ou.y = v1 ? m1 : -1.0f; ov.y = v1 ? n1 : -1.0f;
        ou.z = v2 ? m2 : -1.0f; ov.z = v2 ? n2 : -1.0f;
        ou.w = v3 ? m3 : -1.0f; ov.w = v3 ? n3 : -1.0f;
        __builtin_nontemporal_store(ou, (floatx4*)(oeu + e));
        __builtin_nontemporal_store(ov, (floatx4*)(oev + e));
    }
}

// ---- launch --------------------------------------------------------------
extern "C" void kernel_launch(void* const* d_in, const int* in_sizes, int n_in,
                              void* d_out, int out_size, void* d_ws, size_t ws_size,
                              hipStream_t stream) {
    const float* x  = (const float*)d_in[0];
    const int*   ei = (const int*)d_in[1];
    const float* w  = (const float*)d_in[2];
    float* out = (float*)d_out;

    char* p = (char*)d_ws;
    double* d_norm = (double*)p;                          p += 16;
    unsigned long long* key64   = (unsigned long long*)p; p += (size_t)N_NODES * 8;
    unsigned long long* slotKey = (unsigned long long*)p; p += (size_t)N_NODES * 8;
    float* mappingF = (float*)p; p += (size_t)N_NODES * 4;
    int*   slotIdx  = (int*)p;   p += (size_t)N_NODES * 4;
    int*   perm     = (int*)p;   p += (size_t)K_SEL * 4;
    float* selDot   = (float*)p; p += (size_t)K_SEL * 4;
    int*   hist     = (int*)p;   p += (size_t)NBUCKET * 4;
    int*   counter  = (int*)p;   p += 16;                 /* adjacent to hist */
    int*   start    = (int*)p;   p += (size_t)NBUCKET * 4;
    int*   chunkSums= (int*)p;   p += (size_t)NCHUNK * 4;
    int*   chunkOff = (int*)p;   p += (size_t)NCHUNK * 4;

    /* leading KERNEL (not memset) — absorbs harness fill drain; zeroes
       hist+counter and computes ||w|| */
    init_kernel<<<NBUCKET / 256, 256, 0, stream>>>(w, d_norm, hist, counter);

    int waves_blocks = (N_NODES * 64 + 255) / 256;
    score_kernel<<<waves_blocks, 256, 0, stream>>>(x, w, key64, hist);

    scan_kernel<<<NCHUNK, 256, 0, stream>>>(hist, start, chunkSums, chunkOff, counter);

    int node_blocks = (N_NODES + 255) / 256;
    scatter_kernel<<<node_blocks, 256, 0, stream>>>(key64, start, chunkOff,
                                                    slotKey, slotIdx);

    rank_kernel<<<node_blocks, 256, 0, stream>>>(slotKey, slotIdx, start, hist,
                                                 chunkOff, mappingF, perm, selDot);

    out_kernel<<<GATHER_BLOCKS + EDGE_BLOCKS, 256, 0, stream>>>(x, perm, selDot, d_norm,
                                                                ei, mappingF, out);
}

// Round 8
// 307.243 us; speedup vs baseline: 1.1009x; 1.1009x over previous
//
#include <hip/hip_runtime.h>
#include <math.h>

#define N_NODES 100000
#define N_FEAT  256
#define K_SEL   50000
#define N_EDGES 3200000
#define NBUCKET 65536
#define NCHUNK  256                         /* NBUCKET / 256 bins per chunk */

#define GATHER_BLOCKS (K_SEL / 4)           /* 4 rows (64 lanes ea) per 256-thr block */
#define EDGE_BLOCKS   (N_EDGES / (4 * 256)) /* 4 edges per thread */

typedef float __attribute__((ext_vector_type(4))) floatx4;
typedef int   __attribute__((ext_vector_type(4))) intx4;

// ---- key encodings -------------------------------------------------------
// ascending uint64 key == descending z, so stable-ascending == top_k order
__device__ __forceinline__ unsigned long long descKey(double z) {
    unsigned long long u = (unsigned long long)__double_as_longlong(z);
    unsigned long long a = (u >> 63) ? ~u : (u | 0x8000000000000000ULL);
    return ~a;
}

__device__ __forceinline__ unsigned int bucketOfFloat(float zf) {
    unsigned int u = __float_as_uint(zf);
    unsigned int a = (u >> 31) ? ~u : (u | 0x80000000u);
    return (~a) >> 16;
}

// ---- kernels -------------------------------------------------------------
// zero hist (65536 ints, 1/thread) + zero scan counter + block 0: ||w|| fp64
__global__ void init_kernel(const float* __restrict__ w, double* __restrict__ norm,
                            int* __restrict__ hist, int* __restrict__ counter) {
    __shared__ double sd[256];
    int t = blockIdx.x * blockDim.x + threadIdx.x;
    hist[t] = 0;
    if (t == 0) counter[0] = 0;
    if (blockIdx.x == 0) {
        int tt = threadIdx.x;
        double v = (double)w[tt];
        sd[tt] = v * v;
        __syncthreads();
        for (int off = 128; off > 0; off >>= 1) {
            if (tt < off) sd[tt] += sd[tt + off];
            __syncthreads();
        }
        if (tt == 0) norm[0] = sqrt(sd[0]);
    }
}

// one wave per row: 64 lanes x float4 = 256 features, fp64 accumulate.
// ranking is monotone in the raw dot product -> no norm, no tanh here.
__global__ void score_kernel(const float* __restrict__ x, const float* __restrict__ w,
                             unsigned long long* __restrict__ key64,
                             float* __restrict__ dotf, int* __restrict__ hist) {
    int row  = (int)((blockIdx.x * blockDim.x + threadIdx.x) >> 6);
    int lane = threadIdx.x & 63;
    if (row >= N_NODES) return;
    const float4 xv = ((const float4*)(x + (size_t)row * N_FEAT))[lane];
    const float4 wv = ((const float4*)w)[lane];
    double acc = (double)xv.x * (double)wv.x + (double)xv.y * (double)wv.y +
                 (double)xv.z * (double)wv.z + (double)xv.w * (double)wv.w;
    for (int m = 32; m >= 1; m >>= 1) acc += __shfl_xor(acc, m, 64);
    if (lane == 0) {
        key64[row] = descKey(acc);
        float df = (float)acc;
        dotf[row] = df;
        atomicAdd(&hist[bucketOfFloat(df)], 1);
    }
}

// 256-block chunked scan: each block scans its 256 bins into chunk-LOCAL
// exclusive prefixes (written to start[]); last-arriving block scans the 256
// chunk totals into chunkOff[].  Consumers add chunkOff[b>>8] on the fly.
__global__ void __launch_bounds__(256) scan_kernel(const int* __restrict__ hist,
                                                   int* __restrict__ start,
                                                   int* __restrict__ chunkSums,
                                                   int* __restrict__ chunkOff,
                                                   int* __restrict__ counter) {
    __shared__ int s[256];
    __shared__ int lastFlag;
    int c = blockIdx.x, t = threadIdx.x;
    int v = hist[c * 256 + t];
    s[t] = v;
    __syncthreads();
    for (int off = 1; off < 256; off <<= 1) {
        int add = (t >= off) ? s[t - off] : 0;
        __syncthreads();
        s[t] += add;
        __syncthreads();
    }
    start[c * 256 + t] = s[t] - v; /* chunk-local exclusive prefix */
    if (t == 0) {
        atomicExch(&chunkSums[c], s[255]);   /* device-scope publish */
        __threadfence();
        int old = atomicAdd(counter, 1);
        lastFlag = (old == NCHUNK - 1);
    }
    __syncthreads();
    if (!lastFlag) return;
    /* last block: all 256 chunk sums are published; scan them */
    int w = atomicAdd(&chunkSums[t], 0);     /* device-coherent read */
    __syncthreads();
    s[t] = w;
    __syncthreads();
    for (int off = 1; off < 256; off <<= 1) {
        int add = (t >= off) ? s[t - off] : 0;
        __syncthreads();
        s[t] += add;
        __syncthreads();
    }
    chunkOff[t] = s[t] - w; /* global exclusive offset of chunk t */
}

// scatter nodes to their bucket's slot range; consumes start[] via atomicAdd
__global__ void scatter_kernel(const unsigned long long* __restrict__ key64,
                               const float* __restrict__ dotf,
                               int* __restrict__ start,
                               const int* __restrict__ chunkOff,
                               unsigned long long* __restrict__ slotKey,
                               int* __restrict__ slotIdx) {
    int i = blockIdx.x * blockDim.x + threadIdx.x;
    if (i >= N_NODES) return;
    int b = (int)bucketOfFloat(dotf[i]);
    int pos = atomicAdd(&start[b], 1) + chunkOff[b >> 8];
    slotKey[pos] = key64[i];
    slotIdx[pos] = i;
}

// exact rank within bucket via fp64 key + index tie-break.
// post-scatter start[b]+chunkOff == bucket end; begin = end - hist[b].
// buckets entirely below the cutoff (st >= K) short-circuit to mapping=-1.
__global__ void rank_kernel(const unsigned long long* __restrict__ slotKey,
                            const int* __restrict__ slotIdx,
                            const int* __restrict__ start, const int* __restrict__ hist,
                            const int* __restrict__ chunkOff,
                            const float* __restrict__ dotf,
                            int* __restrict__ mapping, int* __restrict__ perm,
                            float* __restrict__ selDot) {
    int s = blockIdx.x * blockDim.x + threadIdx.x;
    if (s >= N_NODES) return;
    int i = slotIdx[s];
    float df = dotf[i];
    int b = (int)bucketOfFloat(df);
    int end = start[b] + chunkOff[b >> 8];
    int cnt = hist[b];
    int st = end - cnt;
    if (st >= K_SEL) { /* whole bucket below cutoff: no rank needed */
        mapping[i] = -1;
        return;
    }
    int rank = 0;
    if (cnt > 1) {
        unsigned long long myKey = slotKey[s];
        for (int t = st; t < end; ++t) {
            unsigned long long k = slotKey[t];
            if (k < myKey || (k == myKey && slotIdx[t] < i)) ++rank;
        }
    }
    int p = st + rank;
    if (p < K_SEL) {
        mapping[i] = p;
        perm[p] = i;
        selDot[p] = df;
    } else {
        mapping[i] = -1;
    }
}

// fused output: blocks [0,GATHER_BLOCKS) gather+gate x rows (tanh here, fp32,
// selected rows only); blocks [GATHER_BLOCKS,...) remap edges, 4/thread int4
__global__ void out_kernel(const float* __restrict__ x, const int* __restrict__ perm,
                           const float* __restrict__ selDot,
                           const double* __restrict__ normp,
                           const int* __restrict__ ei, const int* __restrict__ mapping,
                           float* __restrict__ out) {
    if (blockIdx.x < GATHER_BLOCKS) {
        int tid = blockIdx.x * 256 + threadIdx.x;
        int r = tid >> 6;
        int c = (tid & 63) << 2;
        int src = perm[r];
        float sc = tanhf(selDot[r] / (float)normp[0]);
        float4 v = *(const float4*)(x + (size_t)src * N_FEAT + c);
        floatx4 o;
        o.x = v.x * sc; o.y = v.y * sc; o.z = v.z * sc; o.w = v.w * sc;
        __builtin_nontemporal_store(o, (floatx4*)(out + (size_t)r * N_FEAT + c));
    } else {
        int tid = (blockIdx.x - GATHER_BLOCKS) * 256 + threadIdx.x;
        int e = tid << 2;
        intx4 a = __builtin_nontemporal_load((const intx4*)(ei + e));
        intx4 b = __builtin_nontemporal_load((const intx4*)(ei + N_EDGES + e));
        float* oeu = out + (size_t)K_SEL * N_FEAT;
        float* oev = oeu + N_EDGES;
        int m0 = mapping[a.x], m1 = mapping[a.y], m2 = mapping[a.z], m3 = mapping[a.w];
        int n0 = mapping[b.x], n1 = mapping[b.y], n2 = mapping[b.z], n3 = mapping[b.w];
        floatx4 ou, ov;
        bool v0 = (m0 >= 0) && (n0 >= 0);
        bool v1 = (m1 >= 0) && (n1 >= 0);
        bool v2 = (m2 >= 0) && (n2 >= 0);
        bool v3 = (m3 >= 0) && (n3 >= 0);
        ou.x = v0 ? (float)m0 : -1.0f; ov.x = v0 ? (float)n0 : -1.0f;
        ou.y = v1 ? (float)m1 : -1.0f; ov.y = v1 ? (float)n1 : -1.0f;
        ou.z = v2 ? (float)m2 : -1.0f; ov.z = v2 ? (float)n2 : -1.0f;
        ou.w = v3 ? (float)m3 : -1.0f; ov.w = v3 ? (float)n3 : -1.0f;
        __builtin_nontemporal_store(ou, (floatx4*)(oeu + e));
        __builtin_nontemporal_store(ov, (floatx4*)(oev + e));
    }
}

// ---- launch --------------------------------------------------------------
extern "C" void kernel_launch(void* const* d_in, const int* in_sizes, int n_in,
                              void* d_out, int out_size, void* d_ws, size_t ws_size,
                              hipStream_t stream) {
    const float* x  = (const float*)d_in[0];
    const int*   ei = (const int*)d_in[1];
    const float* w  = (const float*)d_in[2];
    float* out = (float*)d_out;

    char* p = (char*)d_ws;
    double* d_norm = (double*)p;                          p += 16;
    unsigned long long* key64   = (unsigned long long*)p; p += (size_t)N_NODES * 8;
    unsigned long long* slotKey = (unsigned long long*)p; p += (size_t)N_NODES * 8;
    float* dotf    = (float*)p; p += (size_t)N_NODES * 4;
    int*   mapping = (int*)p;   p += (size_t)N_NODES * 4;
    int*   slotIdx = (int*)p;   p += (size_t)N_NODES * 4;
    int*   perm    = (int*)p;   p += (size_t)K_SEL * 4;
    float* selDot  = (float*)p; p += (size_t)K_SEL * 4;
    int*   hist    = (int*)p;   p += (size_t)NBUCKET * 4;
    int*   start   = (int*)p;   p += (size_t)NBUCKET * 4;
    int*   chunkSums = (int*)p; p += (size_t)NCHUNK * 4;
    int*   chunkOff  = (int*)p; p += (size_t)NCHUNK * 4;
    int*   counter   = (int*)p; p += 16;

    init_kernel<<<NBUCKET / 256, 256, 0, stream>>>(w, d_norm, hist, counter);

    int waves_blocks = (N_NODES * 64 + 255) / 256;
    score_kernel<<<waves_blocks, 256, 0, stream>>>(x, w, key64, dotf, hist);

    scan_kernel<<<NCHUNK, 256, 0, stream>>>(hist, start, chunkSums, chunkOff, counter);

    int node_blocks = (N_NODES + 255) / 256;
    scatter_kernel<<<node_blocks, 256, 0, stream>>>(key64, dotf, start, chunkOff,
                                                    slotKey, slotIdx);

    rank_kernel<<<node_blocks, 256, 0, stream>>>(slotKey, slotIdx, start, hist,
                                                 chunkOff, dotf, mapping, perm, selDot);

    out_kernel<<<GATHER_BLOCKS + EDGE_BLOCKS, 256, 0, stream>>>(x, perm, selDot, d_norm,
                                                                ei, mapping, out);
}